// Round 1
// baseline (20.631 us; speedup 1.0000x reference)
//
#include <hip/hip_runtime.h>

// QIL quantize one weight element.
// ref: p = max(p,0); s = 127/(c-p)
//      wq = |w|<p ? 0 : round(clip((|w|-p)*s*sign(w), -127, 127))
//      out = (|wq|/s + p) * sign(wq)       // NOTE: sign of wq, so wq==0 -> 0
__device__ __forceinline__ float qil1(float w, float p, float s) {
    float aw = fabsf(w);
    // non-pruned branch magnitude: (aw-p)*s >= 0, clip upper at 127, round (half-even)
    float q = rintf(fminf((aw - p) * s, 127.0f));
    float mag = q / s + p;                   // IEEE div matches numpy
    // zero if pruned (|w|<p) or rounded level is 0 (sign(wq)==0)
    return (aw < p || q == 0.0f) ? 0.0f : copysignf(mag, w);
}

__global__ void __launch_bounds__(192)
qil_embed_kernel(const int* __restrict__ x,
                 const float* __restrict__ weight,
                 const float* __restrict__ pp,
                 const float* __restrict__ cp,
                 float* __restrict__ out,
                 int n_tokens, int dim4) {
    // wave-uniform scalars (L2-cached scalar loads)
    const float p = fmaxf(pp[0], 0.0f);
    const float c = cp[0];
    const float s = 127.0f / (c - p);

    const int token = blockIdx.x;
    if (token >= n_tokens) return;
    const long long row = (long long)x[token];   // uniform scalar load

    const float4* __restrict__ src =
        reinterpret_cast<const float4*>(weight) + row * dim4;
    float4* __restrict__ dst =
        reinterpret_cast<float4*>(out) + (long long)token * dim4;

    const int t = threadIdx.x;          // 0..dim4-1 (192), 16B/lane coalesced
    float4 v = src[t];
    float4 r;
    r.x = qil1(v.x, p, s);
    r.y = qil1(v.y, p, s);
    r.z = qil1(v.z, p, s);
    r.w = qil1(v.w, p, s);
    dst[t] = r;

    // tuple outputs 1 and 2: weight_scaling_factor, p
    if (token == 0 && t == 0) {
        const long long total = (long long)n_tokens * (long long)dim4 * 4;
        out[total]     = s;
        out[total + 1] = p;
    }
}

extern "C" void kernel_launch(void* const* d_in, const int* in_sizes, int n_in,
                              void* d_out, int out_size, void* d_ws, size_t ws_size,
                              hipStream_t stream) {
    const int*   x  = (const int*)d_in[0];
    const float* w  = (const float*)d_in[1];
    const float* pp = (const float*)d_in[2];
    const float* cp = (const float*)d_in[3];
    float* out = (float*)d_out;

    const int n_tokens = in_sizes[0];               // 8*2048 = 16384
    const int dim  = (out_size - 2) / n_tokens;     // 768
    const int dim4 = dim / 4;                       // 192 threads/block (3 waves)

    qil_embed_kernel<<<dim3(n_tokens), dim3(dim4), 0, stream>>>(
        x, w, pp, cp, out, n_tokens, dim4);
}

// Round 3
// 20.476 us; speedup vs baseline: 1.0076x; 1.0076x over previous
//
#include <hip/hip_runtime.h>

typedef float f32x4 __attribute__((ext_vector_type(4)));

// QIL quantize one weight element.
// ref: p = max(p,0); s = 127/(c-p)
//      wq = |w|<p ? 0 : round(clip((|w|-p)*s*sign(w), -127, 127))
//      out = (|wq|/s + p) * sign(wq)   // sign of wq: rounded-to-0 -> exactly 0
__device__ __forceinline__ float qil1(float w, float p, float s, float inv_s) {
    float aw = fabsf(w);
    float q = rintf(fminf((aw - p) * s, 127.0f));   // half-even round == jnp.round
    float mag = fmaf(q, inv_s, p);                  // q/s + p (~1ulp vs IEEE div)
    return (aw < p || q == 0.0f) ? 0.0f : copysignf(mag, w);
}

__device__ __forceinline__ f32x4 qil4(f32x4 v, float p, float s, float inv_s) {
    f32x4 r;
    r.x = qil1(v.x, p, s, inv_s);
    r.y = qil1(v.y, p, s, inv_s);
    r.z = qil1(v.z, p, s, inv_s);
    r.w = qil1(v.w, p, s, inv_s);
    return r;
}

// One wave per token. dim = 768 floats = 192 f32x4; lane covers cols
// {lane, lane+64, lane+128} -> 3 independent 16B loads/stores in flight.
__global__ void __launch_bounds__(256)
qil_embed_kernel(const int* __restrict__ x,
                 const float* __restrict__ weight,
                 const float* __restrict__ pp,
                 const float* __restrict__ cp,
                 float* __restrict__ out,
                 int n_tokens, int dim4) {
    const float p     = fmaxf(pp[0], 0.0f);
    const float s     = 127.0f / (cp[0] - p);
    const float inv_s = 1.0f / s;

    const int tok  = (blockIdx.x << 2) | (threadIdx.x >> 6);  // wave id = token
    const int lane = threadIdx.x & 63;
    if (tok >= n_tokens) return;

    const long long row = (long long)x[tok];
    const f32x4* __restrict__ src = (const f32x4*)weight + row * dim4;
    f32x4* __restrict__ dst = (f32x4*)out + (long long)tok * dim4;

    // dim4 = 192 = 3 * 64
    f32x4 v0 = src[lane];
    f32x4 v1 = src[lane + 64];
    f32x4 v2 = src[lane + 128];

    f32x4 r0 = qil4(v0, p, s, inv_s);
    f32x4 r1 = qil4(v1, p, s, inv_s);
    f32x4 r2 = qil4(v2, p, s, inv_s);

    // non-temporal: keep L2 for the weight-row reads
    __builtin_nontemporal_store(r0, dst + lane);
    __builtin_nontemporal_store(r1, dst + lane + 64);
    __builtin_nontemporal_store(r2, dst + lane + 128);

    // tuple outputs 1 and 2: weight_scaling_factor, pruning point
    if (tok == 0 && lane == 0) {
        const long long total = (long long)n_tokens * dim4 * 4;
        out[total]     = s;
        out[total + 1] = p;
    }
}

extern "C" void kernel_launch(void* const* d_in, const int* in_sizes, int n_in,
                              void* d_out, int out_size, void* d_ws, size_t ws_size,
                              hipStream_t stream) {
    const int*   x  = (const int*)d_in[0];
    const float* w  = (const float*)d_in[1];
    const float* pp = (const float*)d_in[2];
    const float* cp = (const float*)d_in[3];
    float* out = (float*)d_out;

    const int n_tokens = in_sizes[0];            // 16384
    const int dim  = (out_size - 2) / n_tokens;  // 768
    const int dim4 = dim / 4;                    // 192

    const int blocks = (n_tokens + 3) / 4;       // 4 waves/block, 1 token/wave
    qil_embed_kernel<<<dim3(blocks), dim3(256), 0, stream>>>(
        x, w, pp, cp, out, n_tokens, dim4);
}

// Round 4
// 20.380 us; speedup vs baseline: 1.0123x; 1.0047x over previous
//
#include <hip/hip_runtime.h>

typedef float f32x4 __attribute__((ext_vector_type(4)));

// QIL quantize one weight element.
// ref: p = max(p,0); s = 127/(c-p)
//      wq = |w|<p ? 0 : round(clip((|w|-p)*s*sign(w), -127, 127))
//      out = (|wq|/s + p) * sign(wq)   // sign of wq: rounded-to-0 -> exactly 0
__device__ __forceinline__ float qil1(float w, float p, float s, float inv_s) {
    float aw = fabsf(w);
    float q = rintf(fminf((aw - p) * s, 127.0f));   // half-even round == jnp.round
    float mag = fmaf(q, inv_s, p);                  // q/s + p (~1ulp vs IEEE div)
    return (aw < p || q == 0.0f) ? 0.0f : copysignf(mag, w);
}

__device__ __forceinline__ f32x4 qil4(f32x4 v, float p, float s, float inv_s) {
    f32x4 r;
    r.x = qil1(v.x, p, s, inv_s);
    r.y = qil1(v.y, p, s, inv_s);
    r.z = qil1(v.z, p, s, inv_s);
    r.w = qil1(v.w, p, s, inv_s);
    return r;
}

// One wave per 2 tokens: 2 independent idx loads -> 6 independent 16B row
// loads in flight -> 6 nt stores. dim = 768 floats = 192 f32x4 = 3*64.
// Rows forced wave-uniform (readfirstlane) -> scalar base + small voffset.
__global__ void __launch_bounds__(256)
qil_embed_kernel(const int* __restrict__ x,
                 const float* __restrict__ weight,
                 const float* __restrict__ pp,
                 const float* __restrict__ cp,
                 float* __restrict__ out,
                 int n_tokens, int dim4) {
    const float p     = fmaxf(pp[0], 0.0f);
    const float s     = 127.0f / (cp[0] - p);
    const float inv_s = 1.0f / s;

    const int wid  = __builtin_amdgcn_readfirstlane(threadIdx.x >> 6);
    const int lane = threadIdx.x & 63;
    const int tok0 = blockIdx.x * 8 + wid * 2;   // 2 tokens per wave
    if (tok0 >= n_tokens) return;

    // both index loads issued before any row load (independent misses)
    const int row0 = __builtin_amdgcn_readfirstlane(x[tok0]);
    const int row1 = __builtin_amdgcn_readfirstlane(x[tok0 + 1]);

    const f32x4* __restrict__ src0 = (const f32x4*)weight + row0 * dim4;
    const f32x4* __restrict__ src1 = (const f32x4*)weight + row1 * dim4;
    f32x4* __restrict__ dst = (f32x4*)out + tok0 * dim4;

    // 6 independent loads in flight
    f32x4 a0 = src0[lane];
    f32x4 a1 = src0[lane + 64];
    f32x4 a2 = src0[lane + 128];
    f32x4 b0 = src1[lane];
    f32x4 b1 = src1[lane + 64];
    f32x4 b2 = src1[lane + 128];

    __builtin_nontemporal_store(qil4(a0, p, s, inv_s), dst + lane);
    __builtin_nontemporal_store(qil4(a1, p, s, inv_s), dst + lane + 64);
    __builtin_nontemporal_store(qil4(a2, p, s, inv_s), dst + lane + 128);
    __builtin_nontemporal_store(qil4(b0, p, s, inv_s), dst + lane + 192);
    __builtin_nontemporal_store(qil4(b1, p, s, inv_s), dst + lane + 256);
    __builtin_nontemporal_store(qil4(b2, p, s, inv_s), dst + lane + 320);

    // tuple outputs 1 and 2: weight_scaling_factor, pruning point
    if (tok0 == 0 && lane == 0) {
        const long long total = (long long)n_tokens * dim4 * 4;
        out[total]     = s;
        out[total + 1] = p;
    }
}

extern "C" void kernel_launch(void* const* d_in, const int* in_sizes, int n_in,
                              void* d_out, int out_size, void* d_ws, size_t ws_size,
                              hipStream_t stream) {
    const int*   x  = (const int*)d_in[0];
    const float* w  = (const float*)d_in[1];
    const float* pp = (const float*)d_in[2];
    const float* cp = (const float*)d_in[3];
    float* out = (float*)d_out;

    const int n_tokens = in_sizes[0];            // 16384
    const int dim  = (out_size - 2) / n_tokens;  // 768
    const int dim4 = dim / 4;                    // 192

    // 256 threads = 4 waves = 8 tokens per block
    const int blocks = (n_tokens + 7) / 8;       // 2048
    qil_embed_kernel<<<dim3(blocks), dim3(256), 0, stream>>>(
        x, w, pp, cp, out, n_tokens, dim4);
}